// Round 2
// baseline (372.711 us; speedup 1.0000x reference)
//
#include <hip/hip_runtime.h>
#include <stdint.h>

#define N_COLS 524288
#define N_PRIMES 168
#define COLS_PER_THREAD 4
#define BLOCK 256
#define ROW_CHUNKS 8          // grid.y for streaming kernel
#define CG_TOTAL (N_COLS / 4) // 131072 float4 column-groups

// primes below 1000 — compile-time constants so % p lowers to magic-multiply
static constexpr uint32_t PRIMES[N_PRIMES] = {
      2,   3,   5,   7,  11,  13,  17,  19,  23,  29,
     31,  37,  41,  43,  47,  53,  59,  61,  67,  71,
     73,  79,  83,  89,  97, 101, 103, 107, 109, 113,
    127, 131, 137, 139, 149, 151, 157, 163, 167, 173,
    179, 181, 191, 193, 197, 199, 211, 223, 227, 229,
    233, 239, 241, 251, 257, 263, 269, 271, 277, 281,
    283, 293, 307, 311, 313, 317, 331, 337, 347, 349,
    353, 359, 367, 373, 379, 383, 389, 397, 401, 409,
    419, 421, 431, 433, 439, 443, 449, 457, 461, 463,
    467, 479, 487, 491, 499, 503, 509, 521, 523, 541,
    547, 557, 563, 569, 571, 577, 587, 593, 599, 601,
    607, 613, 617, 619, 631, 641, 643, 647, 653, 659,
    661, 673, 677, 683, 691, 701, 709, 719, 727, 733,
    739, 743, 751, 757, 761, 769, 773, 787, 797, 809,
    811, 821, 823, 827, 829, 839, 853, 857, 859, 863,
    877, 881, 883, 887, 907, 911, 919, 929, 937, 941,
    947, 953, 967, 971, 977, 983, 991, 997
};

// Kernel A: compute prime-mask weight & bias tables once into workspace.
// ws layout: float4 w[CG_TOTAL] followed by float4 b[CG_TOTAL]  (4 MB total).
__global__ __launch_bounds__(BLOCK) void bwl_prime_mask(
    const float* __restrict__ kern,
    const float* __restrict__ bias,
    float4* __restrict__ wsw,
    float4* __restrict__ wsb)
{
    const int tid = blockIdx.x * BLOCK + threadIdx.x;   // column-group index
    const uint32_t col0 = (uint32_t)tid * COLS_PER_THREAD;

    float w0 = 0.f, w1 = 0.f, w2 = 0.f, w3 = 0.f;
    float b0 = 0.f, b1 = 0.f, b2 = 0.f, b3 = 0.f;
#pragma unroll
    for (int i = 0; i < N_PRIMES; ++i) {
        const uint32_t p = PRIMES[i];       // compile-time constant
        const int rowoff = i * 1000;        // compile-time constant
        uint32_t m0 = col0 % p;             // magic-multiply
        uint32_t m1 = m0 + 1; if (m1 == p) m1 = 0;
        uint32_t m2 = m1 + 1; if (m2 == p) m2 = 0;
        uint32_t m3 = m2 + 1; if (m3 == p) m3 = 0;
        w0 += kern[rowoff + (int)m0];  b0 += bias[rowoff + (int)m0];
        w1 += kern[rowoff + (int)m1];  b1 += bias[rowoff + (int)m1];
        w2 += kern[rowoff + (int)m2];  b2 += bias[rowoff + (int)m2];
        w3 += kern[rowoff + (int)m3];  b3 += bias[rowoff + (int)m3];
    }
    wsw[tid] = make_float4(w0, w1, w2, w3);
    wsb[tid] = make_float4(b0, b1, b2, b3);
}

// Kernel B: pure streaming. grid = (512, ROW_CHUNKS). Each thread owns one
// float4 column-group and 8 rows; w/b loaded once (L2-resident 4 MB table),
// then 8 independent load->fma->store iterations (all loads in flight).
__global__ __launch_bounds__(BLOCK) void bwl_prime_stream(
    const float* __restrict__ x,
    const float4* __restrict__ wsw,
    const float4* __restrict__ wsb,
    float* __restrict__ out,
    int B)
{
    const int cg = blockIdx.x * BLOCK + threadIdx.x;    // column-group
    const int r0 = blockIdx.y * (64 / ROW_CHUNKS);      // 8 rows per thread

    const float4 w = wsw[cg];
    const float4 b = wsb[cg];

    const float4* __restrict__ x4 = (const float4*)x;
    float4* __restrict__ o4 = (float4*)out;

#pragma unroll
    for (int i = 0; i < 64 / ROW_CHUNKS; ++i) {
        const size_t off = (size_t)(r0 + i) * CG_TOTAL + cg;
        float4 xv = x4[off];
        float4 ov;
        ov.x = fmaf(xv.x, w.x, b.x);
        ov.y = fmaf(xv.y, w.y, b.y);
        ov.z = fmaf(xv.z, w.z, b.z);
        ov.w = fmaf(xv.w, w.w, b.w);
        o4[off] = ov;
    }
}

// Fallback (round-1 fused kernel) if workspace is too small.
__global__ __launch_bounds__(BLOCK) void bwl_prime_fused(
    const float* __restrict__ x,
    const float* __restrict__ kern,
    const float* __restrict__ bias,
    float* __restrict__ out,
    int B)
{
    const int tid  = blockIdx.x * BLOCK + threadIdx.x;
    const uint32_t col0 = (uint32_t)tid * COLS_PER_THREAD;

    float w0 = 0.f, w1 = 0.f, w2 = 0.f, w3 = 0.f;
    float b0 = 0.f, b1 = 0.f, b2 = 0.f, b3 = 0.f;
#pragma unroll
    for (int i = 0; i < N_PRIMES; ++i) {
        const uint32_t p = PRIMES[i];
        const int rowoff = i * 1000;
        uint32_t m0 = col0 % p;
        uint32_t m1 = m0 + 1; if (m1 == p) m1 = 0;
        uint32_t m2 = m1 + 1; if (m2 == p) m2 = 0;
        uint32_t m3 = m2 + 1; if (m3 == p) m3 = 0;
        w0 += kern[rowoff + (int)m0];  b0 += bias[rowoff + (int)m0];
        w1 += kern[rowoff + (int)m1];  b1 += bias[rowoff + (int)m1];
        w2 += kern[rowoff + (int)m2];  b2 += bias[rowoff + (int)m2];
        w3 += kern[rowoff + (int)m3];  b3 += bias[rowoff + (int)m3];
    }

    const float4* __restrict__ x4 = (const float4*)x;
    float4* __restrict__ o4 = (float4*)out;
#pragma unroll 4
    for (int r = 0; r < B; ++r) {
        const size_t off = (size_t)r * CG_TOTAL + tid;
        float4 xv = x4[off];
        float4 ov;
        ov.x = fmaf(xv.x, w0, b0);
        ov.y = fmaf(xv.y, w1, b1);
        ov.z = fmaf(xv.z, w2, b2);
        ov.w = fmaf(xv.w, w3, b3);
        o4[off] = ov;
    }
}

extern "C" void kernel_launch(void* const* d_in, const int* in_sizes, int n_in,
                              void* d_out, int out_size, void* d_ws, size_t ws_size,
                              hipStream_t stream) {
    const float* x    = (const float*)d_in[0];
    const float* kern = (const float*)d_in[1];
    const float* bias = (const float*)d_in[2];
    float* out = (float*)d_out;

    const int B = in_sizes[0] / N_COLS;   // 64
    const size_t need = (size_t)2 * CG_TOTAL * sizeof(float4);  // 4 MB

    if (ws_size >= need) {
        float4* wsw = (float4*)d_ws;
        float4* wsb = wsw + CG_TOTAL;
        bwl_prime_mask<<<CG_TOTAL / BLOCK, BLOCK, 0, stream>>>(kern, bias, wsw, wsb);
        dim3 grid(CG_TOTAL / BLOCK, ROW_CHUNKS);
        bwl_prime_stream<<<grid, BLOCK, 0, stream>>>(x, wsw, wsb, out, B);
    } else {
        bwl_prime_fused<<<CG_TOTAL / BLOCK, BLOCK, 0, stream>>>(x, kern, bias, out, B);
    }
}

// Round 3
// 293.234 us; speedup vs baseline: 1.2710x; 1.2710x over previous
//
#include <hip/hip_runtime.h>
#include <stdint.h>

#define N_COLS 524288
#define N_PRIMES 168
#define BLOCK 256
#define ROW_CHUNKS 8            // grid.y for streaming kernel
#define CG_TOTAL (N_COLS / 4)   // 131072 float4 column-groups
#define GTHREADS (N_COLS / 4)   // mask threads: each owns 4 spread columns
#define PCHUNK 21               // primes per grid-y chunk (8 * 21 = 168)

// primes below 1000 — compile-time constants so % p lowers to magic-multiply
static constexpr uint32_t PRIMES[N_PRIMES] = {
      2,   3,   5,   7,  11,  13,  17,  19,  23,  29,
     31,  37,  41,  43,  47,  53,  59,  61,  67,  71,
     73,  79,  83,  89,  97, 101, 103, 107, 109, 113,
    127, 131, 137, 139, 149, 151, 157, 163, 167, 173,
    179, 181, 191, 193, 197, 199, 211, 223, 227, 229,
    233, 239, 241, 251, 257, 263, 269, 271, 277, 281,
    283, 293, 307, 311, 313, 317, 331, 337, 347, 349,
    353, 359, 367, 373, 379, 383, 389, 397, 401, 409,
    419, 421, 431, 433, 439, 443, 449, 457, 461, 463,
    467, 479, 487, 491, 499, 503, 509, 521, 523, 541,
    547, 557, 563, 569, 571, 577, 587, 593, 599, 601,
    607, 613, 617, 619, 631, 641, 643, 647, 653, 659,
    661, 673, 677, 683, 691, 701, 709, 719, 727, 733,
    739, 743, 751, 757, 761, 769, 773, 787, 797, 809,
    811, 821, 823, 827, 829, 839, 853, 857, 859, 863,
    877, 881, 883, 887, 907, 911, 919, 929, 937, 941,
    947, 953, 967, 971, 977, 983, 991, 997
};

// Zero the 4 MB workspace (w table + b table), 1M floats = 262144 float4.
__global__ __launch_bounds__(BLOCK) void bwl_zero_ws(float4* __restrict__ ws)
{
    const int g = blockIdx.x * BLOCK + threadIdx.x;
    ws[g] = make_float4(0.f, 0.f, 0.f, 0.f);
}

// Accumulate 21 primes [I0, I0+21) for thread g's 4 spread columns.
// Template param keeps every prime a compile-time constant (magic-mul mod).
template <int I0>
__device__ __forceinline__ void accum21(uint32_t g,
                                        const float* __restrict__ kern,
                                        const float* __restrict__ bias,
                                        float* w, float* b)
{
#pragma unroll
    for (int j = 0; j < PCHUNK; ++j) {
        const uint32_t p = PRIMES[I0 + j];          // compile-time constant
        const int off = (I0 + j) * 1000;            // compile-time constant
        const uint32_t d = GTHREADS % p;            // compile-time constant
        uint32_t m = g % p;                         // magic-multiply
        w[0] += kern[off + (int)m];  b[0] += bias[off + (int)m];
        m += d; if (m >= p) m -= p;
        w[1] += kern[off + (int)m];  b[1] += bias[off + (int)m];
        m += d; if (m >= p) m -= p;
        w[2] += kern[off + (int)m];  b[2] += bias[off + (int)m];
        m += d; if (m >= p) m -= p;
        w[3] += kern[off + (int)m];  b[3] += bias[off + (int)m];
    }
}

// Kernel A: mask partials. grid = (512, 8). Thread g owns columns
// {g, g+131072, g+262144, g+393216} — lane-contiguous so gathers and the
// atomic stores are coalesced. Each y-chunk handles 21 primes; partial sums
// combined via device-scope atomicAdd into ws (zeroed beforehand).
__global__ __launch_bounds__(BLOCK) void bwl_prime_mask(
    const float* __restrict__ kern,
    const float* __restrict__ bias,
    float* __restrict__ wsw,
    float* __restrict__ wsb)
{
    const uint32_t g = blockIdx.x * BLOCK + threadIdx.x;   // 0..131071
    float w[4] = {0.f, 0.f, 0.f, 0.f};
    float b[4] = {0.f, 0.f, 0.f, 0.f};

    switch (blockIdx.y) {
        case 0: accum21<  0>(g, kern, bias, w, b); break;
        case 1: accum21< 21>(g, kern, bias, w, b); break;
        case 2: accum21< 42>(g, kern, bias, w, b); break;
        case 3: accum21< 63>(g, kern, bias, w, b); break;
        case 4: accum21< 84>(g, kern, bias, w, b); break;
        case 5: accum21<105>(g, kern, bias, w, b); break;
        case 6: accum21<126>(g, kern, bias, w, b); break;
        default: accum21<147>(g, kern, bias, w, b); break;
    }

#pragma unroll
    for (int q = 0; q < 4; ++q) {
        atomicAdd(&wsw[g + q * GTHREADS], w[q]);
        atomicAdd(&wsb[g + q * GTHREADS], b[q]);
    }
}

// Kernel B: pure streaming. grid = (512, ROW_CHUNKS). Each thread owns one
// float4 column-group and 8 rows; w/b loaded once (L2-resident 4 MB table),
// then 8 independent load->fma->store iterations (all loads in flight).
__global__ __launch_bounds__(BLOCK) void bwl_prime_stream(
    const float* __restrict__ x,
    const float4* __restrict__ wsw,
    const float4* __restrict__ wsb,
    float* __restrict__ out)
{
    const int cg = blockIdx.x * BLOCK + threadIdx.x;    // column-group
    const int r0 = blockIdx.y * (64 / ROW_CHUNKS);      // 8 rows per thread

    const float4 w = wsw[cg];
    const float4 b = wsb[cg];

    const float4* __restrict__ x4 = (const float4*)x;
    float4* __restrict__ o4 = (float4*)out;

#pragma unroll
    for (int i = 0; i < 64 / ROW_CHUNKS; ++i) {
        const size_t off = (size_t)(r0 + i) * CG_TOTAL + cg;
        float4 xv = x4[off];
        float4 ov;
        ov.x = fmaf(xv.x, w.x, b.x);
        ov.y = fmaf(xv.y, w.y, b.y);
        ov.z = fmaf(xv.z, w.z, b.z);
        ov.w = fmaf(xv.w, w.w, b.w);
        o4[off] = ov;
    }
}

// Fallback (round-1 fused kernel) if workspace is too small.
__global__ __launch_bounds__(BLOCK) void bwl_prime_fused(
    const float* __restrict__ x,
    const float* __restrict__ kern,
    const float* __restrict__ bias,
    float* __restrict__ out,
    int B)
{
    const int tid  = blockIdx.x * BLOCK + threadIdx.x;
    const uint32_t col0 = (uint32_t)tid * 4;

    float w0 = 0.f, w1 = 0.f, w2 = 0.f, w3 = 0.f;
    float b0 = 0.f, b1 = 0.f, b2 = 0.f, b3 = 0.f;
#pragma unroll
    for (int i = 0; i < N_PRIMES; ++i) {
        const uint32_t p = PRIMES[i];
        const int rowoff = i * 1000;
        uint32_t m0 = col0 % p;
        uint32_t m1 = m0 + 1; if (m1 == p) m1 = 0;
        uint32_t m2 = m1 + 1; if (m2 == p) m2 = 0;
        uint32_t m3 = m2 + 1; if (m3 == p) m3 = 0;
        w0 += kern[rowoff + (int)m0];  b0 += bias[rowoff + (int)m0];
        w1 += kern[rowoff + (int)m1];  b1 += bias[rowoff + (int)m1];
        w2 += kern[rowoff + (int)m2];  b2 += bias[rowoff + (int)m2];
        w3 += kern[rowoff + (int)m3];  b3 += bias[rowoff + (int)m3];
    }

    const float4* __restrict__ x4 = (const float4*)x;
    float4* __restrict__ o4 = (float4*)out;
#pragma unroll 4
    for (int r = 0; r < B; ++r) {
        const size_t off = (size_t)r * CG_TOTAL + tid;
        float4 xv = x4[off];
        float4 ov;
        ov.x = fmaf(xv.x, w0, b0);
        ov.y = fmaf(xv.y, w1, b1);
        ov.z = fmaf(xv.z, w2, b2);
        ov.w = fmaf(xv.w, w3, b3);
        o4[off] = ov;
    }
}

extern "C" void kernel_launch(void* const* d_in, const int* in_sizes, int n_in,
                              void* d_out, int out_size, void* d_ws, size_t ws_size,
                              hipStream_t stream) {
    const float* x    = (const float*)d_in[0];
    const float* kern = (const float*)d_in[1];
    const float* bias = (const float*)d_in[2];
    float* out = (float*)d_out;

    const int B = in_sizes[0] / N_COLS;   // 64
    const size_t need = (size_t)2 * N_COLS * sizeof(float);  // 4 MB

    if (ws_size >= need) {
        float* wsw = (float*)d_ws;
        float* wsb = wsw + N_COLS;

        // zero the accumulator tables (2*524288 floats = 262144 float4)
        bwl_zero_ws<<<(2 * N_COLS / 4) / BLOCK, BLOCK, 0, stream>>>((float4*)d_ws);

        dim3 mgrid(GTHREADS / BLOCK, 8);          // (512, 8)
        bwl_prime_mask<<<mgrid, BLOCK, 0, stream>>>(kern, bias, wsw, wsb);

        dim3 sgrid(CG_TOTAL / BLOCK, ROW_CHUNKS); // (512, 8)
        bwl_prime_stream<<<sgrid, BLOCK, 0, stream>>>(x, (const float4*)wsw,
                                                      (const float4*)wsb, out);
    } else {
        bwl_prime_fused<<<CG_TOTAL / BLOCK, BLOCK, 0, stream>>>(x, kern, bias, out, B);
    }
}